// Round 12
// baseline (893.933 us; speedup 1.0000x reference)
//
#include <hip/hip_runtime.h>
#include <hip/hip_bf16.h>

#define N_E 100000
#define N_C 50000
#define H 256
#define D_E 768
#define D_C 1024
#define E_EE 800000
#define E_EC 400000
#define E_CE 400000
#define E_TOT (E_EE + E_CE + E_EC)

#define ME_PAD 100096  // 782*128
#define MC_PAD 50048   // 391*128

typedef unsigned short u16;
typedef __attribute__((ext_vector_type(8))) short bf16x8;
typedef __attribute__((ext_vector_type(4))) float f32x4;

__device__ __forceinline__ float bf2f(u16 x) {
    unsigned u = ((unsigned)x) << 16;
    return __builtin_bit_cast(float, u);
}
__device__ __forceinline__ u16 f2bf(float f) {
    unsigned u = __builtin_bit_cast(unsigned, f);
    u = (u + 0x7fffu + ((u >> 16) & 1u)) >> 16;
    return (u16)u;
}

// ---------------- weight fragment-packer: 12 jobs ----------------
// in: W[k][n] fp32 (n = 0..255). out: per (nb,kb) fragment of 512 u16,
// elem (l,e) = W[kb*32 + (l>>4)*8 + e][nb*16 + (l&15)]  (matches MFMA B-frag read).
// out index: ((nb*(K/32) + kb)*64 + l)*8 + e
struct PackJobs {
    const float* a[12];
    const float* b[12];  // nullable -> added
    u16* dst[12];
    int K[12];
};

__global__ __launch_bounds__(1024) void pack_w_k(PackJobs t) {
    int j = blockIdx.z;
    int K = t.K[j];
    int k0 = blockIdx.x * 32;
    if (k0 >= K) return;
    int n0 = blockIdx.y * 32;
    __shared__ float sm[32][33];
    int tx = threadIdx.x, ty = threadIdx.y;
    size_t idx = (size_t)(k0 + ty) * H + n0 + tx;
    float v = t.a[j][idx];
    if (t.b[j]) v += t.b[j][idx];
    sm[ty][tx] = v;  // sm[k_local][n_local]
    __syncthreads();
    int tt = ty * 32 + tx;       // 0..1023
    int f = tt >> 9;             // which of 2 n-blocks in this tile
    int q = tt & 511;            // elem within fragment
    int l = q >> 3, e = q & 7;
    int kl = (l >> 4) * 8 + e;
    int nl = f * 16 + (l & 15);
    int nb = (n0 >> 4) + f;
    t.dst[j][((size_t)(nb * (K / 32) + (k0 >> 5)) << 9) + q] = f2bf(sm[kl][nl]);
}

// ---------------- CSR build (merged) ----------------
__global__ __launch_bounds__(256) void hist3_k(const int* __restrict__ eeD,
                                               const int* __restrict__ ceD,
                                               const int* __restrict__ ecD,
                                               int* __restrict__ cnt) {
    int i = blockIdx.x * 256 + threadIdx.x;
    if (i >= E_TOT) return;
    if (i < E_EE) atomicAdd(&cnt[eeD[i]], 1);
    else if (i < E_EE + E_CE) atomicAdd(&cnt[N_E + ceD[i - E_EE]], 1);
    else atomicAdd(&cnt[2 * N_E + ecD[i - E_EE - E_CE]], 1);
}

#define SCAN_N (2 * N_E + N_C)  // 250000
#define SCAN_NB ((SCAN_N + 1023) / 1024)

__global__ __launch_bounds__(1024) void scan_blk_k(const int* __restrict__ cnt,
                                                   int* __restrict__ part,
                                                   int* __restrict__ bsum) {
    __shared__ int sm[1024];
    int i = blockIdx.x * 1024 + threadIdx.x;
    int v = (i < SCAN_N) ? cnt[i] : 0;
    sm[threadIdx.x] = v;
    __syncthreads();
    for (int off = 1; off < 1024; off <<= 1) {
        int t = (threadIdx.x >= off) ? sm[threadIdx.x - off] : 0;
        __syncthreads();
        sm[threadIdx.x] += t;
        __syncthreads();
    }
    if (i < SCAN_N) part[i] = sm[threadIdx.x] - v;
    if (threadIdx.x == 1023) bsum[blockIdx.x] = sm[1023];
}

__global__ __launch_bounds__(1024) void scan_top_k(int* __restrict__ bsum) {
    __shared__ int sm[1024];
    int v = (threadIdx.x < SCAN_NB) ? bsum[threadIdx.x] : 0;
    sm[threadIdx.x] = v;
    __syncthreads();
    for (int off = 1; off < 1024; off <<= 1) {
        int t = (threadIdx.x >= off) ? sm[threadIdx.x - off] : 0;
        __syncthreads();
        sm[threadIdx.x] += t;
        __syncthreads();
    }
    if (threadIdx.x < SCAN_NB) bsum[threadIdx.x] = sm[threadIdx.x] - v;
}

__global__ __launch_bounds__(1024) void scan_out_k(const int* __restrict__ part,
                                                   const int* __restrict__ bsum,
                                                   int* __restrict__ eePtr,
                                                   int* __restrict__ cePtr,
                                                   int* __restrict__ ecPtr,
                                                   int* __restrict__ curAll) {
    int i = blockIdx.x * 1024 + threadIdx.x;
    if (i < SCAN_N) {
        int v = part[i] + bsum[blockIdx.x];
        int w;
        if (i < N_E) {
            w = v; eePtr[i] = w;
        } else if (i < 2 * N_E) {
            w = v - E_EE; cePtr[i - N_E] = w;
        } else {
            w = v - (E_EE + E_CE); ecPtr[i - 2 * N_E] = w;
        }
        curAll[i] = w;
    }
    if (i == 0) {
        eePtr[N_E] = E_EE;
        cePtr[N_E] = E_CE;
        ecPtr[N_C] = E_EC;
    }
}

__global__ __launch_bounds__(256) void reorder3_k(const int* __restrict__ eeS, const int* __restrict__ eeD,
                                                  const int* __restrict__ ceS, const int* __restrict__ ceD,
                                                  const int* __restrict__ ecS, const int* __restrict__ ecD,
                                                  int* __restrict__ curAll, int* __restrict__ srcAll) {
    int i = blockIdx.x * 256 + threadIdx.x;
    if (i >= E_TOT) return;
    if (i < E_EE) {
        int pos = atomicAdd(&curAll[eeD[i]], 1);
        srcAll[pos] = eeS[i];
    } else if (i < E_EE + E_CE) {
        int k = i - E_EE;
        int pos = atomicAdd(&curAll[N_E + ceD[k]], 1);
        srcAll[E_EE + pos] = ceS[k];
    } else {
        int k = i - E_EE - E_CE;
        int pos = atomicAdd(&curAll[2 * N_E + ecD[k]], 1);
        srcAll[E_EE + E_CE + pos] = ecS[k];
    }
}

// ---------------- merged gather-mean: 3 jobs per launch ----------------
struct GatherArgs {
    const u16* feat[3];
    const int* rowptr[3];
    const int* srcIdx[3];
    u16* outAgg[3];
    int nDst[3];
    int blkEnd[3];
};

__device__ __forceinline__ void acc8(float* a, uint4 v) {
    a[0] += __builtin_bit_cast(float, v.x << 16);
    a[1] += __builtin_bit_cast(float, v.x & 0xffff0000u);
    a[2] += __builtin_bit_cast(float, v.y << 16);
    a[3] += __builtin_bit_cast(float, v.y & 0xffff0000u);
    a[4] += __builtin_bit_cast(float, v.z << 16);
    a[5] += __builtin_bit_cast(float, v.z & 0xffff0000u);
    a[6] += __builtin_bit_cast(float, v.w << 16);
    a[7] += __builtin_bit_cast(float, v.w & 0xffff0000u);
}

__global__ __launch_bounds__(256) void gather3_k(GatherArgs a) {
    const int b = blockIdx.x;
    const int j = (b >= a.blkEnd[0]) + (b >= a.blkEnd[1]);
    const int b0 = j ? a.blkEnd[j - 1] : 0;
    const int r = (b - b0) * 4 + (threadIdx.x >> 6);
    const int lane = threadIdx.x & 63;
    const int half = lane >> 5;
    const int pos = lane & 31;

    float acc[8] = {};
    int deg = 0;
    if (r < a.nDst[j]) {
        const int* __restrict__ rp = a.rowptr[j];
        const int* __restrict__ si = a.srcIdx[j];
        const u16* __restrict__ ft = a.feat[j];
        int e0 = rp[r], e1 = rp[r + 1];
        deg = e1 - e0;
        int e = e0;
        for (; e + 7 < e1; e += 8) {
            int sA = si[e + half];
            int sB = si[e + 2 + half];
            int sC = si[e + 4 + half];
            int sD = si[e + 6 + half];
            uint4 vA = *(const uint4*)(ft + (size_t)sA * H + pos * 8);
            uint4 vB = *(const uint4*)(ft + (size_t)sB * H + pos * 8);
            uint4 vC = *(const uint4*)(ft + (size_t)sC * H + pos * 8);
            uint4 vD = *(const uint4*)(ft + (size_t)sD * H + pos * 8);
            acc8(acc, vA); acc8(acc, vB); acc8(acc, vC); acc8(acc, vD);
        }
        for (; e + 3 < e1; e += 4) {
            int sA = si[e + half];
            int sB = si[e + 2 + half];
            uint4 vA = *(const uint4*)(ft + (size_t)sA * H + pos * 8);
            uint4 vB = *(const uint4*)(ft + (size_t)sB * H + pos * 8);
            acc8(acc, vA); acc8(acc, vB);
        }
        for (; e + 1 < e1; e += 2) {
            int s = si[e + half];
            uint4 v = *(const uint4*)(ft + (size_t)s * H + pos * 8);
            acc8(acc, v);
        }
        if (e < e1 && half == 0) {
            int s = si[e];
            uint4 v = *(const uint4*)(ft + (size_t)s * H + pos * 8);
            acc8(acc, v);
        }
    }
#pragma unroll
    for (int k = 0; k < 8; ++k) acc[k] += __shfl_xor(acc[k], 32);

    if (half == 0) {
        float inv = deg > 0 ? 1.f / (float)deg : 0.f;
        uint4 o;
        o.x = (unsigned)f2bf(acc[0] * inv) | ((unsigned)f2bf(acc[1] * inv) << 16);
        o.y = (unsigned)f2bf(acc[2] * inv) | ((unsigned)f2bf(acc[3] * inv) << 16);
        o.z = (unsigned)f2bf(acc[4] * inv) | ((unsigned)f2bf(acc[5] * inv) << 16);
        o.w = (unsigned)f2bf(acc[6] * inv) | ((unsigned)f2bf(acc[7] * inv) << 16);
        *(uint4*)(a.outAgg[j] + (size_t)r * H + pos * 8) = o;
    }
}

// ================= conv GEMM (K=H=256): A via LDS (2-buf, 1-step lead), B from L2 regs ========
// Per step: 4 B-frag loads (coalesced 1KB/wave from frag-packed weights, L2-hit) ->
// sched_barrier -> 1 gload_lds A(s+1) -> vmcnt(1) [drains B(s)+A(s), keeps A(s+1)].
// LDS traffic/step: 8KB stage + 32KB A-reads (vs 88KB with LDS-B).
struct GemmCfg {
    const u16* A[3];
    const u16* Wf[3];    // fragment-packed, ((nb*8 + kb)*64 + lane)*8 u16
    int nPairs;
    const float* bias1;
    const float* bias2;
    const u16* res;
    void* out;
    int Mvalid;
    int mode;  // 1 = relu(acc+b)+res -> bf16 ; 2 = l2norm(acc+b) -> fp32
};
struct ConvArgs2 {
    GemmCfg c[2];
    int blkSplit;
};

__global__ __launch_bounds__(512, 4) void gemm_conv_k(ConvArgs2 gg) {
    const int which = blockIdx.x >= gg.blkSplit;
    const GemmCfg* __restrict__ g = which ? &gg.c[1] : &gg.c[0];
    const int row0 = (blockIdx.x - (which ? gg.blkSplit : 0)) * 128;

    __shared__ char ldsA[2][8192];
    __shared__ float rowsq[128];
    const int tid = threadIdx.x;
    const int lane = tid & 63;
    const int wid = tid >> 6;
    const int wm = wid >> 2;
    const int wn = wid & 3;

    const int srow = tid >> 2;
    const int au = (tid & 3) ^ ((srow >> 1) & 3);
    const int ofsA = (row0 + srow) * H + au * 8;

    int a_off[4];
#pragma unroll
    for (int mi = 0; mi < 4; ++mi) {
        int row = wm * 64 + mi * 16 + (lane & 15);
        int u = (lane >> 4) ^ ((row >> 1) & 3);
        a_off[mi] = row * 64 + u * 16;
    }
    const int bofs = lane * 8;  // within-fragment element offset

#define STAGEA(p_, kk_, buf_)                                                                     \
    __builtin_amdgcn_global_load_lds(                                                             \
        (const __attribute__((address_space(1))) void*)(g->A[p_] + ofsA + (kk_)),                 \
        (__attribute__((address_space(3))) void*)((buf_) + wid * 1024), 16, 0, 0)

    f32x4 acc[4][4] = {};
    const int T = g->nPairs * 8;  // K=256 -> 8 kb-steps per pair

    STAGEA(0, 0, ldsA[0]);
    int pn = 0, kn = 32;  // A source for step 1
    if (kn == H) { kn = 0; pn = 1; }
    int bp = 0, bk = 0;   // B source for step s

    for (int s = 0; s < T; ++s) {
        const int ph = s & 1;
        // ---- B(s) fragment loads (must be OLDEST in FIFO this step) ----
        const u16* Wf = g->Wf[bp];
        bf16x8 bc0 = *(const bf16x8*)(Wf + ((wn * 4 + 0) * 8 + bk) * 512 + bofs);
        bf16x8 bc1 = *(const bf16x8*)(Wf + ((wn * 4 + 1) * 8 + bk) * 512 + bofs);
        bf16x8 bc2 = *(const bf16x8*)(Wf + ((wn * 4 + 2) * 8 + bk) * 512 + bofs);
        bf16x8 bc3 = *(const bf16x8*)(Wf + ((wn * 4 + 3) * 8 + bk) * 512 + bofs);
        if (++bk == 8) { bk = 0; ++bp; }
        __builtin_amdgcn_sched_barrier(0);  // pin B-loads before A-stage
        if (s + 1 < T) {
            STAGEA(pn, kn, ldsA[ph ^ 1]);
            kn += 32;
            if (kn == H) { kn = 0; ++pn; }
            asm volatile("s_waitcnt vmcnt(1)" ::: "memory");  // drain B(s)+A(s); keep A(s+1)
        } else {
            asm volatile("s_waitcnt vmcnt(0)" ::: "memory");
        }
        __builtin_amdgcn_sched_barrier(0);
        __builtin_amdgcn_s_barrier();  // A(s) tile ready for all waves

        bf16x8 af[4];
#pragma unroll
        for (int mi = 0; mi < 4; ++mi)
            af[mi] = *reinterpret_cast<const bf16x8*>(ldsA[ph] + a_off[mi]);
#pragma unroll
        for (int mi = 0; mi < 4; ++mi) {
            acc[mi][0] = __builtin_amdgcn_mfma_f32_16x16x32_bf16(af[mi], bc0, acc[mi][0], 0, 0, 0);
            acc[mi][1] = __builtin_amdgcn_mfma_f32_16x16x32_bf16(af[mi], bc1, acc[mi][1], 0, 0, 0);
            acc[mi][2] = __builtin_amdgcn_mfma_f32_16x16x32_bf16(af[mi], bc2, acc[mi][2], 0, 0, 0);
            acc[mi][3] = __builtin_amdgcn_mfma_f32_16x16x32_bf16(af[mi], bc3, acc[mi][3], 0, 0, 0);
        }
        __builtin_amdgcn_sched_barrier(0);
        __builtin_amdgcn_s_barrier();  // reads of ldsA[ph] done -> next stage may overwrite
    }
#undef STAGEA

    // ---- epilogue: D mapping col = lane&15, row = (lane>>4)*4 + j ----
    const int ccol = wn * 64 + (lane & 15);
    const int crow0 = row0 + wm * 64 + ((lane >> 4) << 2);
    float bv[4];
#pragma unroll
    for (int ni = 0; ni < 4; ++ni) {
        int c = ccol + ni * 16;
        float b = 0.f;
        if (g->bias1) b += g->bias1[c];
        if (g->bias2) b += g->bias2[c];
        bv[ni] = b;
    }

    if (g->mode == 1) {
#pragma unroll
        for (int ni = 0; ni < 4; ++ni) {
            int c = ccol + ni * 16;
#pragma unroll
            for (int mi = 0; mi < 4; ++mi) {
#pragma unroll
                for (int j = 0; j < 4; ++j) {
                    int r = crow0 + mi * 16 + j;
                    size_t idx = (size_t)r * H + c;
                    float v = fmaxf(acc[mi][ni][j] + bv[ni], 0.f) + bf2f(g->res[idx]);
                    ((u16*)g->out)[idx] = f2bf(v);
                }
            }
        }
    } else {
        if (tid < 128) rowsq[tid] = 0.f;
        __syncthreads();
#pragma unroll
        for (int mi = 0; mi < 4; ++mi) {
#pragma unroll
            for (int j = 0; j < 4; ++j) {
                float p = 0.f;
#pragma unroll
                for (int ni = 0; ni < 4; ++ni) {
                    float v = acc[mi][ni][j] + bv[ni];
                    p += v * v;
                }
                p += __shfl_xor(p, 1);
                p += __shfl_xor(p, 2);
                p += __shfl_xor(p, 4);
                p += __shfl_xor(p, 8);
                if ((lane & 15) == 0) {
                    int rl = wm * 64 + mi * 16 + ((lane >> 4) << 2) + j;
                    atomicAdd(&rowsq[rl], p);
                }
            }
        }
        __syncthreads();
#pragma unroll
        for (int mi = 0; mi < 4; ++mi) {
#pragma unroll
            for (int j = 0; j < 4; ++j) {
                int rl = wm * 64 + mi * 16 + ((lane >> 4) << 2) + j;
                int r = row0 + rl;
                if (r < g->Mvalid) {
                    float inv = 1.f / fmaxf(sqrtf(rowsq[rl]), 1e-12f);
#pragma unroll
                    for (int ni = 0; ni < 4; ++ni) {
                        int c = ccol + ni * 16;
                        float v = acc[mi][ni][j] + bv[ni];
                        ((float*)g->out)[(size_t)r * H + c] = v * inv;
                    }
                }
            }
        }
    }
}

// ================= projection GEMM: fp32 A (in-kernel cvt, LDS), B from L2 regs ===============
struct ProjArgs2 {
    const float* A[2];
    const u16* Wf[2];  // fragment-packed
    int K[2];
    int M[2];
    u16* out[2];
    int blkSplit;
};

__global__ __launch_bounds__(512, 4) void gemm_proj_k(ProjArgs2 gg) {
    const int which = blockIdx.x >= gg.blkSplit;
    const int row0 = (blockIdx.x - (which ? gg.blkSplit : 0)) * 128;
    const float* __restrict__ Aptr = gg.A[which];
    const u16* __restrict__ Wf = gg.Wf[which];
    const int K = gg.K[which];
    const int KB = K >> 5;
    const int M = gg.M[which];
    u16* __restrict__ outp = gg.out[which];

    __shared__ char ldsA[2][8192];
    const int tid = threadIdx.x;
    const int lane = tid & 63;
    const int wid = tid >> 6;
    const int wm = wid >> 2;
    const int wn = wid & 3;

    const int srow = tid >> 2;
    const int cunit = tid & 3;
    const int aRow = min(row0 + srow, M - 1);
    const float* pA = Aptr + (size_t)aRow * K + cunit * 8;
    const int aDst = srow * 64 + (cunit ^ ((srow >> 1) & 3)) * 16;

    int a_off[4];
#pragma unroll
    for (int mi = 0; mi < 4; ++mi) {
        int row = wm * 64 + mi * 16 + (lane & 15);
        int u = (lane >> 4) ^ ((row >> 1) & 3);
        a_off[mi] = row * 64 + u * 16;
    }
    const u16* bbase = Wf + (size_t)(wn * 4) * KB * 512 + lane * 8;

    f32x4 acc[4][4] = {};
    const int T = KB;

    // prologue: A(0) into c-regs
    float4 c0 = *reinterpret_cast<const float4*>(pA);
    float4 c1 = *reinterpret_cast<const float4*>(pA + 4);

    for (int s = 0; s < T; ++s) {
        const int ph = s & 1;
        // ---- B(s) loads first (oldest in FIFO) ----
        bf16x8 bc0 = *(const bf16x8*)(bbase + (0 * KB + s) * 512);
        bf16x8 bc1 = *(const bf16x8*)(bbase + (1 * KB + s) * 512);
        bf16x8 bc2 = *(const bf16x8*)(bbase + (2 * KB + s) * 512);
        bf16x8 bc3 = *(const bf16x8*)(bbase + (3 * KB + s) * 512);
        __builtin_amdgcn_sched_barrier(0);
        // ---- cvt A(s) (compiler waits on c-regs) + write to LDS ----
        union { bf16x8 v; u16 e[8]; } pk;
        pk.e[0] = f2bf(c0.x); pk.e[1] = f2bf(c0.y); pk.e[2] = f2bf(c0.z); pk.e[3] = f2bf(c0.w);
        pk.e[4] = f2bf(c1.x); pk.e[5] = f2bf(c1.y); pk.e[6] = f2bf(c1.z); pk.e[7] = f2bf(c1.w);
        *reinterpret_cast<bf16x8*>(ldsA[ph] + aDst) = pk.v;
        // ---- A(s+1) into c-regs (after ds_write consumed them) ----
        if (s + 1 < T) {
            c0 = *reinterpret_cast<const float4*>(pA + (s + 1) * 32);
            c1 = *reinterpret_cast<const float4*>(pA + (s + 1) * 32 + 4);
            asm volatile("s_waitcnt vmcnt(2)" ::: "memory");  // drain B(s); keep A(s+1)
        } else {
            asm volatile("s_waitcnt vmcnt(0)" ::: "memory");
        }
        asm volatile("s_waitcnt lgkmcnt(0)" ::: "memory");
        __builtin_amdgcn_sched_barrier(0);
        __builtin_amdgcn_s_barrier();

        bf16x8 af[4];
#pragma unroll
        for (int mi = 0; mi < 4; ++mi)
            af[mi] = *reinterpret_cast<const bf16x8*>(ldsA[ph] + a_off[mi]);
#pragma unroll
        for (int mi = 0; mi < 4; ++mi) {
            acc[mi][0] = __builtin_amdgcn_mfma_f32_16x16x32_bf16(af[mi], bc0, acc[mi][0], 0, 0, 0);
            acc[mi][1] = __builtin_amdgcn_mfma_f32_16x16x32_bf16(af[mi], bc1, acc[mi][1], 0, 0, 0);
            acc[mi][2] = __builtin_amdgcn_mfma_f32_16x16x32_bf16(af[mi], bc2, acc[mi][2], 0, 0, 0);
            acc[mi][3] = __builtin_amdgcn_mfma_f32_16x16x32_bf16(af[mi], bc3, acc[mi][3], 0, 0, 0);
        }
        __builtin_amdgcn_sched_barrier(0);
        __builtin_amdgcn_s_barrier();
    }

    const int ccol = wn * 64 + (lane & 15);
    const int crow0 = row0 + wm * 64 + ((lane >> 4) << 2);
#pragma unroll
    for (int ni = 0; ni < 4; ++ni) {
        int c = ccol + ni * 16;
#pragma unroll
        for (int mi = 0; mi < 4; ++mi) {
#pragma unroll
            for (int j = 0; j < 4; ++j) {
                int r = crow0 + mi * 16 + j;
                outp[(size_t)r * H + c] = f2bf(acc[mi][ni][j]);
            }
        }
    }
}

extern "C" void kernel_launch(void* const* d_in, const int* in_sizes, int n_in,
                              void* d_out, int out_size, void* d_ws, size_t ws_size,
                              hipStream_t stream) {
    const float* x_e = (const float*)d_in[0];
    const float* x_c = (const float*)d_in[1];
    const int* e_ee = (const int*)d_in[2];
    const int* e_ec = (const int*)d_in[3];
    const int* e_ce = (const int*)d_in[4];
    const float* P_e = (const float*)d_in[5];
    const float* P_c = (const float*)d_in[6];
    const float* Wl1 = (const float*)d_in[7];
    const float* bl1 = (const float*)d_in[8];
    const float* Wr1 = (const float*)d_in[9];
    const float* Wl2 = (const float*)d_in[10];
    const float* bl2 = (const float*)d_in[11];
    const float* Wr2 = (const float*)d_in[12];
    float* out = (float*)d_out;

    const size_t EHp = (size_t)ME_PAD * H;
    const size_t CHp = (size_t)MC_PAD * H;

    u16* us = (u16*)d_ws;
    u16* he0 = us;   us += EHp;
    u16* he1 = us;   us += EHp;
    u16* aggE1 = us; us += EHp;
    u16* aggE2 = us; us += EHp;
    u16* hc0 = us;   us += CHp;
    u16* hc1 = us;   us += CHp;
    u16* aggC = us;  us += CHp;
    u16* PeF = us;   us += H * D_E;
    u16* PcF = us;   us += H * D_C;
    u16* WlF1 = us;  us += 3 * H * H;
    u16* WrF1_1 = us; us += H * H;
    u16* WrF1s = us;  us += H * H;
    u16* WlF2 = us;  us += 3 * H * H;
    u16* WrF2_1 = us; us += H * H;
    u16* WrF2s = us;  us += H * H;

    int* ip = (int*)us;
    int* eePtr = ip;  ip += N_E + 1;
    int* cePtr = ip;  ip += N_E + 1;
    int* ecPtr = ip;  ip += N_C + 1;
    int* curAll = ip; ip += SCAN_N;
    int* srcAll = ip; ip += E_TOT;
    int* cntAll = ip; ip += SCAN_N;
    int* part = ip;   ip += SCAN_N;
    int* bsum = ip;   ip += SCAN_NB + 1;

    const int WHH = H * H;

    // --- CSR build ---
    hipMemsetAsync(cntAll, 0, (size_t)SCAN_N * sizeof(int), stream);
    hist3_k<<<(E_TOT + 255) / 256, 256, 0, stream>>>(e_ee + E_EE, e_ce + E_CE, e_ec + E_EC, cntAll);
    scan_blk_k<<<SCAN_NB, 1024, 0, stream>>>(cntAll, part, bsum);
    scan_top_k<<<1, 1024, 0, stream>>>(bsum);
    scan_out_k<<<SCAN_NB, 1024, 0, stream>>>(part, bsum, eePtr, cePtr, ecPtr, curAll);
    reorder3_k<<<(E_TOT + 255) / 256, 256, 0, stream>>>(e_ee, e_ee + E_EE, e_ce, e_ce + E_CE,
                                                        e_ec, e_ec + E_EC, curAll, srcAll);
    const int* eeSrc = srcAll;
    const int* ceSrc = srcAll + E_EE;
    const int* ecSrc = srcAll + E_EE + E_CE;

    // --- weight prep: fragment-pack 12 jobs ---
    {
        PackJobs t{};
        int n = 0;
        auto add = [&](const float* a, const float* b, u16* d, int K) {
            t.a[n] = a; t.b[n] = b; t.dst[n] = d; t.K[n] = K; ++n;
        };
        add(P_e, nullptr, PeF, D_E);
        add(P_c, nullptr, PcF, D_C);
        for (int p = 0; p < 3; ++p) add(Wl1 + p * WHH, nullptr, WlF1 + p * WHH, H);
        for (int p = 0; p < 3; ++p) add(Wl2 + p * WHH, nullptr, WlF2 + p * WHH, H);
        add(Wr1 + 1 * WHH, nullptr, WrF1_1, H);
        add(Wr2 + 1 * WHH, nullptr, WrF2_1, H);
        add(Wr1 + 0 * WHH, Wr1 + 2 * WHH, WrF1s, H);
        add(Wr2 + 0 * WHH, Wr2 + 2 * WHH, WrF2s, H);
        pack_w_k<<<dim3(D_C / 32, H / 32, 12), dim3(32, 32), 0, stream>>>(t);
    }

    const int gridE = ME_PAD / 128, gridC = MC_PAD / 128;

    // --- projections (merged) ---
    {
        ProjArgs2 g{};
        g.A[0] = x_e; g.Wf[0] = PeF; g.K[0] = D_E; g.M[0] = N_E; g.out[0] = he0;
        g.A[1] = x_c; g.Wf[1] = PcF; g.K[1] = D_C; g.M[1] = N_C; g.out[1] = hc0;
        g.blkSplit = gridE;
        gemm_proj_k<<<gridE + gridC, 512, 0, stream>>>(g);
    }

    const int gBlkE = ME_PAD / 4, gBlkC = MC_PAD / 4;
    const int gTotal = 2 * gBlkE + gBlkC;

    // --- conv1 ---
    {
        GatherArgs a{};
        a.feat[0] = he0; a.rowptr[0] = eePtr; a.srcIdx[0] = eeSrc; a.outAgg[0] = aggE1; a.nDst[0] = N_E;
        a.feat[1] = hc0; a.rowptr[1] = cePtr; a.srcIdx[1] = ceSrc; a.outAgg[1] = aggE2; a.nDst[1] = N_E;
        a.feat[2] = he0; a.rowptr[2] = ecPtr; a.srcIdx[2] = ecSrc; a.outAgg[2] = aggC;  a.nDst[2] = N_C;
        a.blkEnd[0] = gBlkE; a.blkEnd[1] = 2 * gBlkE; a.blkEnd[2] = gTotal;
        gather3_k<<<gTotal, 256, 0, stream>>>(a);
    }
    {
        ConvArgs2 g{};
        g.c[0].A[0] = aggE1; g.c[0].Wf[0] = WlF1 + 0 * WHH;
        g.c[0].A[1] = aggE2; g.c[0].Wf[1] = WlF1 + 2 * WHH;
        g.c[0].A[2] = he0;   g.c[0].Wf[2] = WrF1s;
        g.c[0].nPairs = 3;
        g.c[0].bias1 = bl1 + 0 * H; g.c[0].bias2 = bl1 + 2 * H;
        g.c[0].res = he0; g.c[0].out = he1; g.c[0].Mvalid = N_E; g.c[0].mode = 1;
        g.c[1].A[0] = aggC; g.c[1].Wf[0] = WlF1 + 1 * WHH;
        g.c[1].A[1] = hc0;  g.c[1].Wf[1] = WrF1_1;
        g.c[1].nPairs = 2;
        g.c[1].bias1 = bl1 + 1 * H;
        g.c[1].res = hc0; g.c[1].out = hc1; g.c[1].Mvalid = N_C; g.c[1].mode = 1;
        g.blkSplit = gridE;
        gemm_conv_k<<<gridE + gridC, 512, 0, stream>>>(g);
    }

    // --- conv2 (fused l2norm, direct to d_out) ---
    {
        GatherArgs a{};
        a.feat[0] = he1; a.rowptr[0] = eePtr; a.srcIdx[0] = eeSrc; a.outAgg[0] = aggE1; a.nDst[0] = N_E;
        a.feat[1] = hc1; a.rowptr[1] = cePtr; a.srcIdx[1] = ceSrc; a.outAgg[1] = aggE2; a.nDst[1] = N_E;
        a.feat[2] = he1; a.rowptr[2] = ecPtr; a.srcIdx[2] = ecSrc; a.outAgg[2] = aggC;  a.nDst[2] = N_C;
        a.blkEnd[0] = gBlkE; a.blkEnd[1] = 2 * gBlkE; a.blkEnd[2] = gTotal;
        gather3_k<<<gTotal, 256, 0, stream>>>(a);
    }
    {
        ConvArgs2 g{};
        g.c[0].A[0] = aggE1; g.c[0].Wf[0] = WlF2 + 0 * WHH;
        g.c[0].A[1] = aggE2; g.c[0].Wf[1] = WlF2 + 2 * WHH;
        g.c[0].A[2] = he1;   g.c[0].Wf[2] = WrF2s;
        g.c[0].nPairs = 3;
        g.c[0].bias1 = bl2 + 0 * H; g.c[0].bias2 = bl2 + 2 * H;
        g.c[0].out = out; g.c[0].Mvalid = N_E; g.c[0].mode = 2;
        g.c[1].A[0] = aggC; g.c[1].Wf[0] = WlF2 + 1 * WHH;
        g.c[1].A[1] = hc1;  g.c[1].Wf[1] = WrF2_1;
        g.c[1].nPairs = 2;
        g.c[1].bias1 = bl2 + 1 * H;
        g.c[1].out = out + (size_t)N_E * H; g.c[1].Mvalid = N_C; g.c[1].mode = 2;
        g.blkSplit = gridE;
        gemm_conv_k<<<gridE + gridC, 512, 0, stream>>>(g);
    }
}

// Round 13
// 840.680 us; speedup vs baseline: 1.0633x; 1.0633x over previous
//
#include <hip/hip_runtime.h>
#include <hip/hip_bf16.h>

#define N_E 100000
#define N_C 50000
#define H 256
#define D_E 768
#define D_C 1024
#define E_EE 800000
#define E_EC 400000
#define E_CE 400000
#define E_TOT (E_EE + E_CE + E_EC)

#define ME_PAD 100096  // 782*128
#define MC_PAD 50048   // 391*128

#define LDSZ 24576  // per-phase LDS: A 8KB @0 | B 16KB @8192

typedef unsigned short u16;
typedef __attribute__((ext_vector_type(8))) short bf16x8;
typedef __attribute__((ext_vector_type(4))) float f32x4;

__device__ __forceinline__ float bf2f(u16 x) {
    unsigned u = ((unsigned)x) << 16;
    return __builtin_bit_cast(float, u);
}
__device__ __forceinline__ u16 f2bf(float f) {
    unsigned u = __builtin_bit_cast(unsigned, f);
    u = (u + 0x7fffu + ((u >> 16) & 1u)) >> 16;
    return (u16)u;
}

// ---------------- merged weight transpose: 12 jobs, [K][256] fp32 -> [256][K] bf16 ----------------
struct TransJobs {
    const float* a[12];
    const float* b[12];  // nullable -> added
    u16* dst[12];
    int K[12];
};

__global__ __launch_bounds__(1024) void transpose_all_k(TransJobs t) {
    int j = blockIdx.z;
    int K = t.K[j];
    int k0 = blockIdx.x * 32;
    if (k0 >= K) return;
    int n0 = blockIdx.y * 32;
    __shared__ float sm[32][33];
    int tx = threadIdx.x, ty = threadIdx.y;
    size_t idx = (size_t)(k0 + ty) * H + n0 + tx;
    float v = t.a[j][idx];
    if (t.b[j]) v += t.b[j][idx];
    sm[ty][tx] = v;
    __syncthreads();
    t.dst[j][(size_t)(n0 + ty) * K + k0 + tx] = f2bf(sm[tx][ty]);
}

#define SCAN_N (2 * N_E + N_C)  // 250000
#define SCAN_NB ((SCAN_N + 1023) / 1024)

__global__ __launch_bounds__(1024) void scan_blk_k(const int* __restrict__ cnt,
                                                   int* __restrict__ part,
                                                   int* __restrict__ bsum) {
    __shared__ int sm[1024];
    int i = blockIdx.x * 1024 + threadIdx.x;
    int v = (i < SCAN_N) ? cnt[i] : 0;
    sm[threadIdx.x] = v;
    __syncthreads();
    for (int off = 1; off < 1024; off <<= 1) {
        int t = (threadIdx.x >= off) ? sm[threadIdx.x - off] : 0;
        __syncthreads();
        sm[threadIdx.x] += t;
        __syncthreads();
    }
    if (i < SCAN_N) part[i] = sm[threadIdx.x] - v;
    if (threadIdx.x == 1023) bsum[blockIdx.x] = sm[1023];
}

__global__ __launch_bounds__(1024) void scan_top_k(int* __restrict__ bsum) {
    __shared__ int sm[1024];
    int v = (threadIdx.x < SCAN_NB) ? bsum[threadIdx.x] : 0;
    sm[threadIdx.x] = v;
    __syncthreads();
    for (int off = 1; off < 1024; off <<= 1) {
        int t = (threadIdx.x >= off) ? sm[threadIdx.x - off] : 0;
        __syncthreads();
        sm[threadIdx.x] += t;
        __syncthreads();
    }
    if (threadIdx.x < SCAN_NB) bsum[threadIdx.x] = sm[threadIdx.x] - v;
}

__global__ __launch_bounds__(1024) void scan_out_k(const int* __restrict__ part,
                                                   const int* __restrict__ bsum,
                                                   int* __restrict__ eePtr,
                                                   int* __restrict__ cePtr,
                                                   int* __restrict__ ecPtr,
                                                   int* __restrict__ curAll) {
    int i = blockIdx.x * 1024 + threadIdx.x;
    if (i < SCAN_N) {
        int v = part[i] + bsum[blockIdx.x];
        int w;
        if (i < N_E) {
            w = v; eePtr[i] = w;
        } else if (i < 2 * N_E) {
            w = v - E_EE; cePtr[i - N_E] = w;
        } else {
            w = v - (E_EE + E_CE); ecPtr[i - 2 * N_E] = w;
        }
        curAll[i] = w;
    }
    if (i == 0) {
        eePtr[N_E] = E_EE;
        cePtr[N_E] = E_CE;
        ecPtr[N_C] = E_EC;
    }
}

__global__ __launch_bounds__(256) void reorder3_k(const int* __restrict__ eeS, const int* __restrict__ eeD,
                                                  const int* __restrict__ ceS, const int* __restrict__ ceD,
                                                  const int* __restrict__ ecS, const int* __restrict__ ecD,
                                                  int* __restrict__ curAll, int* __restrict__ srcAll) {
    int i = blockIdx.x * 256 + threadIdx.x;
    if (i >= E_TOT) return;
    if (i < E_EE) {
        int pos = atomicAdd(&curAll[eeD[i]], 1);
        srcAll[pos] = eeS[i];
    } else if (i < E_EE + E_CE) {
        int k = i - E_EE;
        int pos = atomicAdd(&curAll[N_E + ceD[k]], 1);
        srcAll[E_EE + pos] = ceS[k];
    } else {
        int k = i - E_EE - E_CE;
        int pos = atomicAdd(&curAll[2 * N_E + ecD[k]], 1);
        srcAll[E_EE + E_CE + pos] = ecS[k];
    }
}

// ---------------- merged gather-mean: 3 jobs per launch ----------------
struct GatherArgs {
    const u16* feat[3];
    const int* rowptr[3];
    const int* srcIdx[3];
    u16* outAgg[3];
    int nDst[3];
    int blkEnd[3];
};

__device__ __forceinline__ void acc8(float* a, uint4 v) {
    a[0] += __builtin_bit_cast(float, v.x << 16);
    a[1] += __builtin_bit_cast(float, v.x & 0xffff0000u);
    a[2] += __builtin_bit_cast(float, v.y << 16);
    a[3] += __builtin_bit_cast(float, v.y & 0xffff0000u);
    a[4] += __builtin_bit_cast(float, v.z << 16);
    a[5] += __builtin_bit_cast(float, v.z & 0xffff0000u);
    a[6] += __builtin_bit_cast(float, v.w << 16);
    a[7] += __builtin_bit_cast(float, v.w & 0xffff0000u);
}

__global__ __launch_bounds__(256) void gather3_k(GatherArgs a) {
    const int b = blockIdx.x;
    const int j = (b >= a.blkEnd[0]) + (b >= a.blkEnd[1]);
    const int b0 = j ? a.blkEnd[j - 1] : 0;
    const int r = (b - b0) * 4 + (threadIdx.x >> 6);
    const int lane = threadIdx.x & 63;
    const int half = lane >> 5;
    const int pos = lane & 31;

    float acc[8] = {};
    int deg = 0;
    if (r < a.nDst[j]) {
        const int* __restrict__ rp = a.rowptr[j];
        const int* __restrict__ si = a.srcIdx[j];
        const u16* __restrict__ ft = a.feat[j];
        int e0 = rp[r], e1 = rp[r + 1];
        deg = e1 - e0;
        int e = e0;
        for (; e + 7 < e1; e += 8) {
            int sA = si[e + half];
            int sB = si[e + 2 + half];
            int sC = si[e + 4 + half];
            int sD = si[e + 6 + half];
            uint4 vA = *(const uint4*)(ft + (size_t)sA * H + pos * 8);
            uint4 vB = *(const uint4*)(ft + (size_t)sB * H + pos * 8);
            uint4 vC = *(const uint4*)(ft + (size_t)sC * H + pos * 8);
            uint4 vD = *(const uint4*)(ft + (size_t)sD * H + pos * 8);
            acc8(acc, vA); acc8(acc, vB); acc8(acc, vC); acc8(acc, vD);
        }
        for (; e + 3 < e1; e += 4) {
            int sA = si[e + half];
            int sB = si[e + 2 + half];
            uint4 vA = *(const uint4*)(ft + (size_t)sA * H + pos * 8);
            uint4 vB = *(const uint4*)(ft + (size_t)sB * H + pos * 8);
            acc8(acc, vA); acc8(acc, vB);
        }
        for (; e + 1 < e1; e += 2) {
            int s = si[e + half];
            uint4 v = *(const uint4*)(ft + (size_t)s * H + pos * 8);
            acc8(acc, v);
        }
        if (e < e1 && half == 0) {
            int s = si[e];
            uint4 v = *(const uint4*)(ft + (size_t)s * H + pos * 8);
            acc8(acc, v);
        }
    }
#pragma unroll
    for (int k = 0; k < 8; ++k) acc[k] += __shfl_xor(acc[k], 32);

    if (half == 0) {
        float inv = deg > 0 ? 1.f / (float)deg : 0.f;
        uint4 o;
        o.x = (unsigned)f2bf(acc[0] * inv) | ((unsigned)f2bf(acc[1] * inv) << 16);
        o.y = (unsigned)f2bf(acc[2] * inv) | ((unsigned)f2bf(acc[3] * inv) << 16);
        o.z = (unsigned)f2bf(acc[4] * inv) | ((unsigned)f2bf(acc[5] * inv) << 16);
        o.w = (unsigned)f2bf(acc[6] * inv) | ((unsigned)f2bf(acc[7] * inv) << 16);
        *(uint4*)(a.outAgg[j] + (size_t)r * H + pos * 8) = o;
    }
}

// ================= conv GEMM (K=H=256), triple-buffered 2-deep pipeline (R7/R11 best) =========
struct GemmCfg {
    const u16* A[3];
    const u16* Wt[3];
    int nPairs;
    const float* bias1;
    const float* bias2;
    const u16* res;
    void* out;
    int Mvalid;
    int mode;  // 1 = relu(acc+b)+res -> bf16 ; 2 = l2norm(acc+b) -> fp32
};
struct ConvArgs2 {
    GemmCfg c[2];
    int blkSplit;
};

__global__ __launch_bounds__(512, 4) void gemm_conv_k(ConvArgs2 gg) {
    const int which = blockIdx.x >= gg.blkSplit;
    const GemmCfg* __restrict__ g = which ? &gg.c[1] : &gg.c[0];
    const int row0 = (blockIdx.x - (which ? gg.blkSplit : 0)) * 128;

    __shared__ char lds[3][LDSZ];
    __shared__ float rowsq[128];
    const int tid = threadIdx.x;
    const int lane = tid & 63;
    const int wid = tid >> 6;
    const int wm = wid >> 2;
    const int wn = wid & 3;

    const int srow = tid >> 2;
    const int au = (tid & 3) ^ ((srow >> 1) & 3);
    const int ofsA = (row0 + srow) * H + au * 8;
    const int ofsB1 = srow * H + au * 8;
    const int brow2 = 128 + srow;
    const int bu2 = (tid & 3) ^ ((brow2 >> 1) & 3);
    const int ofsB2 = brow2 * H + bu2 * 8;

    int a_off[4], b_off[4];
#pragma unroll
    for (int mi = 0; mi < 4; ++mi) {
        int row = wm * 64 + mi * 16 + (lane & 15);
        int u = (lane >> 4) ^ ((row >> 1) & 3);
        a_off[mi] = row * 64 + u * 16;
    }
#pragma unroll
    for (int ni = 0; ni < 4; ++ni) {
        int row = wn * 64 + ni * 16 + (lane & 15);
        int u = (lane >> 4) ^ ((row >> 1) & 3);
        b_off[ni] = 8192 + row * 64 + u * 16;
    }

#define STAGE(p_, kk_, buf_)                                                                      \
    do {                                                                                          \
        const u16* A_ = g->A[p_];                                                                 \
        const u16* W_ = g->Wt[p_];                                                                \
        __builtin_amdgcn_global_load_lds(                                                         \
            (const __attribute__((address_space(1))) void*)(A_ + ofsA + (kk_)),                   \
            (__attribute__((address_space(3))) void*)((buf_) + wid * 1024), 16, 0, 0);            \
        __builtin_amdgcn_global_load_lds(                                                         \
            (const __attribute__((address_space(1))) void*)(W_ + ofsB1 + (kk_)),                  \
            (__attribute__((address_space(3))) void*)((buf_) + 8192 + wid * 1024), 16, 0, 0);     \
        __builtin_amdgcn_global_load_lds(                                                         \
            (const __attribute__((address_space(1))) void*)(W_ + ofsB2 + (kk_)),                  \
            (__attribute__((address_space(3))) void*)((buf_) + 16384 + wid * 1024), 16, 0, 0);    \
    } while (0)

    f32x4 acc[4][4] = {};
    const int T = g->nPairs * (H >> 5);

    char* bufC = lds[0];
    char* bufN = lds[1];
    char* bufS = lds[2];

    STAGE(0, 0, bufC);
    STAGE(0, 32, bufN);
    int pn = 0, kn = 64;
    if (kn == H) { kn = 0; pn = 1; }

    for (int s = 0; s < T; ++s) {
        if (s + 2 < T) {
            STAGE(pn, kn, bufS);
            kn += 32;
            if (kn == H) { kn = 0; ++pn; }
            asm volatile("s_waitcnt vmcnt(6)" ::: "memory");
        } else if (s + 1 < T) {
            asm volatile("s_waitcnt vmcnt(3)" ::: "memory");
        } else {
            asm volatile("s_waitcnt vmcnt(0)" ::: "memory");
        }
        __builtin_amdgcn_sched_barrier(0);
        __builtin_amdgcn_s_barrier();

        bf16x8 af[4], bfr[4];
#pragma unroll
        for (int mi = 0; mi < 4; ++mi)
            af[mi] = *reinterpret_cast<const bf16x8*>(bufC + a_off[mi]);
#pragma unroll
        for (int ni = 0; ni < 4; ++ni)
            bfr[ni] = *reinterpret_cast<const bf16x8*>(bufC + b_off[ni]);
#pragma unroll
        for (int mi = 0; mi < 4; ++mi)
#pragma unroll
            for (int ni = 0; ni < 4; ++ni)
                acc[mi][ni] = __builtin_amdgcn_mfma_f32_16x16x32_bf16(af[mi], bfr[ni],
                                                                      acc[mi][ni], 0, 0, 0);
        __builtin_amdgcn_sched_barrier(0);
        __builtin_amdgcn_s_barrier();
        char* t = bufC; bufC = bufN; bufN = bufS; bufS = t;
    }
#undef STAGE

    const int ccol = wn * 64 + (lane & 15);
    const int crow0 = row0 + wm * 64 + ((lane >> 4) << 2);
    float bv[4];
#pragma unroll
    for (int ni = 0; ni < 4; ++ni) {
        int c = ccol + ni * 16;
        float b = 0.f;
        if (g->bias1) b += g->bias1[c];
        if (g->bias2) b += g->bias2[c];
        bv[ni] = b;
    }

    if (g->mode == 1) {
#pragma unroll
        for (int ni = 0; ni < 4; ++ni) {
            int c = ccol + ni * 16;
#pragma unroll
            for (int mi = 0; mi < 4; ++mi) {
#pragma unroll
                for (int j = 0; j < 4; ++j) {
                    int r = crow0 + mi * 16 + j;
                    size_t idx = (size_t)r * H + c;
                    float v = fmaxf(acc[mi][ni][j] + bv[ni], 0.f) + bf2f(g->res[idx]);
                    ((u16*)g->out)[idx] = f2bf(v);
                }
            }
        }
    } else {
        if (tid < 128) rowsq[tid] = 0.f;
        __syncthreads();
#pragma unroll
        for (int mi = 0; mi < 4; ++mi) {
#pragma unroll
            for (int j = 0; j < 4; ++j) {
                float p = 0.f;
#pragma unroll
                for (int ni = 0; ni < 4; ++ni) {
                    float v = acc[mi][ni][j] + bv[ni];
                    p += v * v;
                }
                p += __shfl_xor(p, 1);
                p += __shfl_xor(p, 2);
                p += __shfl_xor(p, 4);
                p += __shfl_xor(p, 8);
                if ((lane & 15) == 0) {
                    int rl = wm * 64 + mi * 16 + ((lane >> 4) << 2) + j;
                    atomicAdd(&rowsq[rl], p);
                }
            }
        }
        __syncthreads();
#pragma unroll
        for (int mi = 0; mi < 4; ++mi) {
#pragma unroll
            for (int j = 0; j < 4; ++j) {
                int rl = wm * 64 + mi * 16 + ((lane >> 4) << 2) + j;
                int r = row0 + rl;
                if (r < g->Mvalid) {
                    float inv = 1.f / fmaxf(sqrtf(rowsq[rl]), 1e-12f);
#pragma unroll
                    for (int ni = 0; ni < 4; ++ni) {
                        int c = ccol + ni * 16;
                        float v = acc[mi][ni][j] + bv[ni];
                        ((float*)g->out)[(size_t)r * H + c] = v * inv;
                    }
                }
            }
        }
    }
}

// ================= projection GEMM (R11) + fused CSR histogram blocks =========================
// blocks [0, nProj): proj GEMM (fp32 A in-kernel cvt, 2-deep pipeline).
// blocks [nProj, ...): histogram over E_TOT edge dsts (runs on CUs idle during proj tail).
struct ProjArgs2 {
    const float* A[2];
    const u16* Wt[2];
    int K[2];
    int M[2];
    u16* out[2];
    int blkSplit;
    int nProj;
    const int* eeD;
    const int* ceD;
    const int* ecD;
    int* cnt;
};

__global__ __launch_bounds__(512, 4) void gemm_proj_hist_k(ProjArgs2 gg) {
    if (blockIdx.x >= gg.nProj) {
        // ---- histogram path: 1024 edges per block (512 thr x 2) ----
        int i = (blockIdx.x - gg.nProj) * 1024 + threadIdx.x;
#pragma unroll
        for (int t = 0; t < 2; ++t, i += 512) {
            if (i < E_TOT) {
                if (i < E_EE) atomicAdd(&gg.cnt[gg.eeD[i]], 1);
                else if (i < E_EE + E_CE) atomicAdd(&gg.cnt[N_E + gg.ceD[i - E_EE]], 1);
                else atomicAdd(&gg.cnt[2 * N_E + gg.ecD[i - E_EE - E_CE]], 1);
            }
        }
        return;
    }

    const int which = blockIdx.x >= gg.blkSplit;
    const int row0 = (blockIdx.x - (which ? gg.blkSplit : 0)) * 128;
    const float* __restrict__ Aptr = gg.A[which];
    const u16* __restrict__ Wt = gg.Wt[which];
    const int K = gg.K[which];
    const int M = gg.M[which];
    u16* __restrict__ outp = gg.out[which];

    __shared__ char lds[3][LDSZ];
    const int tid = threadIdx.x;
    const int lane = tid & 63;
    const int wid = tid >> 6;
    const int wm = wid >> 2;
    const int wn = wid & 3;

    const int srow = tid >> 2;
    const int cunit = tid & 3;
    const int aRow = min(row0 + srow, M - 1);
    const float* pA = Aptr + (size_t)aRow * K + cunit * 8;
    const int aDst = srow * 64 + (cunit ^ ((srow >> 1) & 3)) * 16;

    const int bu1 = cunit ^ ((srow >> 1) & 3);
    const int ofsB1 = srow * K + bu1 * 8;
    const int brow2 = 128 + srow;
    const int bu2 = cunit ^ ((brow2 >> 1) & 3);
    const int ofsB2 = brow2 * K + bu2 * 8;

    int a_off[4], b_off[4];
#pragma unroll
    for (int mi = 0; mi < 4; ++mi) {
        int row = wm * 64 + mi * 16 + (lane & 15);
        int u = (lane >> 4) ^ ((row >> 1) & 3);
        a_off[mi] = row * 64 + u * 16;
    }
#pragma unroll
    for (int ni = 0; ni < 4; ++ni) {
        int row = wn * 64 + ni * 16 + (lane & 15);
        int u = (lane >> 4) ^ ((row >> 1) & 3);
        b_off[ni] = 8192 + row * 64 + u * 16;
    }

#define BSTAGE(kk_, buf_)                                                                         \
    do {                                                                                          \
        __builtin_amdgcn_global_load_lds(                                                         \
            (const __attribute__((address_space(1))) void*)(Wt + ofsB1 + (kk_)),                  \
            (__attribute__((address_space(3))) void*)((buf_) + 8192 + wid * 1024), 16, 0, 0);     \
        __builtin_amdgcn_global_load_lds(                                                         \
            (const __attribute__((address_space(1))) void*)(Wt + ofsB2 + (kk_)),                  \
            (__attribute__((address_space(3))) void*)((buf_) + 16384 + wid * 1024), 16, 0, 0);    \
    } while (0)

    f32x4 acc[4][4] = {};
    const int T = K >> 5;

    char* bufC = lds[0];
    char* bufN = lds[1];
    char* bufS = lds[2];

    BSTAGE(0, bufC);
    float4 cA0 = *reinterpret_cast<const float4*>(pA);
    float4 cA1 = *reinterpret_cast<const float4*>(pA + 4);
    BSTAGE(32, bufN);
    float4 cB0 = *reinterpret_cast<const float4*>(pA + 32);
    float4 cB1 = *reinterpret_cast<const float4*>(pA + 36);

#define PITER(s_, c0_, c1_)                                                                       \
    do {                                                                                          \
        const int s = (s_);                                                                       \
        if (s + 2 < T) {                                                                          \
            BSTAGE((s + 2) * 32, bufS);                                                           \
            asm volatile("s_waitcnt vmcnt(6)" ::: "memory");                                      \
        } else if (s + 1 < T) {                                                                   \
            asm volatile("s_waitcnt vmcnt(4)" ::: "memory");                                      \
        } else {                                                                                  \
            asm volatile("s_waitcnt vmcnt(0)" ::: "memory");                                      \
        }                                                                                         \
        union { bf16x8 v; u16 e[8]; } pk;                                                         \
        pk.e[0] = f2bf(c0_.x); pk.e[1] = f2bf(c0_.y);                                             \
        pk.e[2] = f2bf(c0_.z); pk.e[3] = f2bf(c0_.w);                                             \
        pk.e[4] = f2bf(c1_.x); pk.e[5] = f2bf(c1_.y);                                             \
        pk.e[6] = f2bf(c1_.z); pk.e[7] = f2bf(c1_.w);                                             \
        *reinterpret_cast<bf16x8*>(bufC + aDst) = pk.v;                                           \
        if (s + 2 < T) {                                                                          \
            c0_ = *reinterpret_cast<const float4*>(pA + (s + 2) * 32);                            \
            c1_ = *reinterpret_cast<const float4*>(pA + (s + 2) * 32 + 4);                        \
        }                                                                                         \
        asm volatile("s_waitcnt lgkmcnt(0)" ::: "memory");                                        \
        __builtin_amdgcn_sched_barrier(0);                                                        \
        __builtin_amdgcn_s_barrier();                                                             \
        bf16x8 af[4], bfr[4];                                                                     \
        _Pragma("unroll")                                                                         \
        for (int mi = 0; mi < 4; ++mi)                                                            \
            af[mi] = *reinterpret_cast<const bf16x8*>(bufC + a_off[mi]);                          \
        _Pragma("unroll")                                                                         \
        for (int ni = 0; ni < 4; ++ni)                                                            \
            bfr[ni] = *reinterpret_cast<const bf16x8*>(bufC + b_off[ni]);                         \
        _Pragma("unroll")                                                                         \
        for (int mi = 0; mi < 4; ++mi)                                                            \
            _Pragma("unroll")                                                                     \
            for (int ni = 0; ni < 4; ++ni)                                                        \
                acc[mi][ni] = __builtin_amdgcn_mfma_f32_16x16x32_bf16(af[mi], bfr[ni],            \
                                                                      acc[mi][ni], 0, 0, 0);      \
        __builtin_amdgcn_sched_barrier(0);                                                        \
        __builtin_amdgcn_s_barrier();                                                             \
        char* t_ = bufC; bufC = bufN; bufN = bufS; bufS = t_;                                     \
    } while (0)

    for (int s2 = 0; s2 < T; s2 += 2) {  // T is even (24 or 32)
        PITER(s2, cA0, cA1);
        PITER(s2 + 1, cB0, cB1);
    }
#undef PITER
#undef BSTAGE

    const int ccol = wn * 64 + (lane & 15);
    const int crow0 = row0 + wm * 64 + ((lane >> 4) << 2);
#pragma unroll
    for (int ni = 0; ni < 4; ++ni) {
        int c = ccol + ni * 16;
#pragma unroll
        for (int mi = 0; mi < 4; ++mi) {
#pragma unroll
            for (int j = 0; j < 4; ++j) {
                int r = crow0 + mi * 16 + j;
                outp[(size_t)r * H + c] = f2bf(acc[mi][ni][j]);
            }
        }
    }
}

extern "C" void kernel_launch(void* const* d_in, const int* in_sizes, int n_in,
                              void* d_out, int out_size, void* d_ws, size_t ws_size,
                              hipStream_t stream) {
    const float* x_e = (const float*)d_in[0];
    const float* x_c = (const float*)d_in[1];
    const int* e_ee = (const int*)d_in[2];
    const int* e_ec = (const int*)d_in[3];
    const int* e_ce = (const int*)d_in[4];
    const float* P_e = (const float*)d_in[5];
    const float* P_c = (const float*)d_in[6];
    const float* Wl1 = (const float*)d_in[7];
    const float* bl1 = (const float*)d_in[8];
    const float* Wr1 = (const float*)d_in[9];
    const float* Wl2 = (const float*)d_in[10];
    const float* bl2 = (const float*)d_in[11];
    const float* Wr2 = (const float*)d_in[12];
    float* out = (float*)d_out;

    const size_t EHp = (size_t)ME_PAD * H;
    const size_t CHp = (size_t)MC_PAD * H;

    u16* us = (u16*)d_ws;
    u16* he0 = us;   us += EHp;
    u16* he1 = us;   us += EHp;
    u16* aggE1 = us; us += EHp;
    u16* aggE2 = us; us += EHp;
    u16* hc0 = us;   us += CHp;
    u16* hc1 = us;   us += CHp;
    u16* aggC = us;  us += CHp;
    u16* PeT = us;   us += H * D_E;
    u16* PcT = us;   us += H * D_C;
    u16* WlT1 = us;  us += 3 * H * H;
    u16* WrT1_1 = us; us += H * H;
    u16* WrT1s = us;  us += H * H;
    u16* WlT2 = us;  us += 3 * H * H;
    u16* WrT2_1 = us; us += H * H;
    u16* WrT2s = us;  us += H * H;

    int* ip = (int*)us;
    int* eePtr = ip;  ip += N_E + 1;
    int* cePtr = ip;  ip += N_E + 1;
    int* ecPtr = ip;  ip += N_C + 1;
    int* curAll = ip; ip += SCAN_N;
    int* srcAll = ip; ip += E_TOT;
    int* cntAll = ip; ip += SCAN_N;
    int* part = ip;   ip += SCAN_N;
    int* bsum = ip;   ip += SCAN_NB + 1;

    const int WHH = H * H;

    // --- weight prep + zero counters (both independent of everything else) ---
    hipMemsetAsync(cntAll, 0, (size_t)SCAN_N * sizeof(int), stream);
    {
        TransJobs t{};
        int n = 0;
        auto add = [&](const float* a, const float* b, u16* d, int K) {
            t.a[n] = a; t.b[n] = b; t.dst[n] = d; t.K[n] = K; ++n;
        };
        add(P_e, nullptr, PeT, D_E);
        add(P_c, nullptr, PcT, D_C);
        for (int p = 0; p < 3; ++p) add(Wl1 + p * WHH, nullptr, WlT1 + p * WHH, H);
        for (int p = 0; p < 3; ++p) add(Wl2 + p * WHH, nullptr, WlT2 + p * WHH, H);
        add(Wr1 + 1 * WHH, nullptr, WrT1_1, H);
        add(Wr2 + 1 * WHH, nullptr, WrT2_1, H);
        add(Wr1 + 0 * WHH, Wr1 + 2 * WHH, WrT1s, H);
        add(Wr2 + 0 * WHH, Wr2 + 2 * WHH, WrT2s, H);
        transpose_all_k<<<dim3(D_C / 32, H / 32, 12), dim3(32, 32), 0, stream>>>(t);
    }

    const int gridE = ME_PAD / 128, gridC = MC_PAD / 128;
    const int nProj = gridE + gridC;
    const int nHist = (E_TOT + 1023) / 1024;

    // --- projections + fused CSR histogram ---
    {
        ProjArgs2 g{};
        g.A[0] = x_e; g.Wt[0] = PeT; g.K[0] = D_E; g.M[0] = N_E; g.out[0] = he0;
        g.A[1] = x_c; g.Wt[1] = PcT; g.K[1] = D_C; g.M[1] = N_C; g.out[1] = hc0;
        g.blkSplit = gridE;
        g.nProj = nProj;
        g.eeD = e_ee + E_EE; g.ceD = e_ce + E_CE; g.ecD = e_ec + E_EC;
        g.cnt = cntAll;
        gemm_proj_hist_k<<<nProj + nHist, 512, 0, stream>>>(g);
    }

    // --- CSR scan + reorder (needs histogram; overlapped hist already done) ---
    scan_blk_k<<<SCAN_NB, 1024, 0, stream>>>(cntAll, part, bsum);
    scan_top_k<<<1, 1024, 0, stream>>>(bsum);
    scan_out_k<<<SCAN_NB, 1024, 0, stream>>>(part, bsum, eePtr, cePtr, ecPtr, curAll);
    reorder3_k<<<(E_TOT + 255) / 256, 256, 0, stream>>>(e_ee, e_ee + E_EE, e_ce, e_ce + E_CE,
                                                        e_ec, e_ec + E_EC, curAll, srcAll);
    const int* eeSrc = srcAll;
    const int* ceSrc = srcAll + E_EE;
    const int* ecSrc = srcAll + E_EE + E_CE;

    const int gBlkE = ME_PAD / 4, gBlkC = MC_PAD / 4;
    const int gTotal = 2 * gBlkE + gBlkC;

    // --- conv1 ---
    {
        GatherArgs a{};
        a.feat[0] = he0; a.rowptr[0] = eePtr; a.srcIdx[0] = eeSrc; a.outAgg[0] = aggE1; a.nDst[0] = N_E;
        a.feat[1] = hc0; a.rowptr[1] = cePtr; a.srcIdx[1] = ceSrc; a.outAgg[1] = aggE2; a.nDst[1] = N_E;
        a.feat[2] = he0; a.rowptr[2] = ecPtr; a.srcIdx[2] = ecSrc; a.outAgg[2] = aggC;  a.nDst[2] = N_C;
        a.blkEnd[0] = gBlkE; a.blkEnd[1] = 2 * gBlkE; a.blkEnd[2] = gTotal;
        gather3_k<<<gTotal, 256, 0, stream>>>(a);
    }
    {
        ConvArgs2 g{};
        g.c[0].A[0] = aggE1; g.c[0].Wt[0] = WlT1 + 0 * WHH;
        g.c[0].A[1] = aggE2; g.c[0].Wt[1] = WlT1 + 2 * WHH;
        g.c[0].A[2] = he0;   g.c[0].Wt[2] = WrT1s;
        g.c[0].nPairs = 3;
        g.c[0].bias1 = bl1 + 0 * H; g.c[0].bias2 = bl1 + 2 * H;
        g.c[0].res = he0; g.c[0].out = he1; g.c[0].Mvalid = N_E; g.c[0].mode = 1;
        g.c[1].A[0] = aggC; g.c[1].Wt[0] = WlT1 + 1 * WHH;
        g.c[1].A[1] = hc0;  g.c[1].Wt[1] = WrT1_1;
        g.c[1].nPairs = 2;
        g.c[1].bias1 = bl1 + 1 * H;
        g.c[1].res = hc0; g.c[1].out = hc1; g.c[1].Mvalid = N_C; g.c[1].mode = 1;
        g.blkSplit = gridE;
        gemm_conv_k<<<gridE + gridC, 512, 0, stream>>>(g);
    }

    // --- conv2 (fused l2norm, direct to d_out) ---
    {
        GatherArgs a{};
        a.feat[0] = he1; a.rowptr[0] = eePtr; a.srcIdx[0] = eeSrc; a.outAgg[0] = aggE1; a.nDst[0] = N_E;
        a.feat[1] = hc1; a.rowptr[1] = cePtr; a.srcIdx[1] = ceSrc; a.outAgg[1] = aggE2; a.nDst[1] = N_E;
        a.feat[2] = he1; a.rowptr[2] = ecPtr; a.srcIdx[2] = ecSrc; a.outAgg[2] = aggC;  a.nDst[2] = N_C;
        a.blkEnd[0] = gBlkE; a.blkEnd[1] = 2 * gBlkE; a.blkEnd[2] = gTotal;
        gather3_k<<<gTotal, 256, 0, stream>>>(a);
    }
    {
        ConvArgs2 g{};
        g.c[0].A[0] = aggE1; g.c[0].Wt[0] = WlT2 + 0 * WHH;
        g.c[0].A[1] = aggE2; g.c[0].Wt[1] = WlT2 + 2 * WHH;
        g.c[0].A[2] = he1;   g.c[0].Wt[2] = WrT2s;
        g.c[0].nPairs = 3;
        g.c[0].bias1 = bl2 + 0 * H; g.c[0].bias2 = bl2 + 2 * H;
        g.c[0].out = out; g.c[0].Mvalid = N_E; g.c[0].mode = 2;
        g.c[1].A[0] = aggC; g.c[1].Wt[0] = WlT2 + 1 * WHH;
        g.c[1].A[1] = hc1;  g.c[1].Wt[1] = WrT2_1;
        g.c[1].nPairs = 2;
        g.c[1].bias1 = bl2 + 1 * H;
        g.c[1].out = out + (size_t)N_E * H; g.c[1].Mvalid = N_C; g.c[1].mode = 2;
        g.blkSplit = gridE;
        gemm_conv_k<<<gridE + gridC, 512, 0, stream>>>(g);
    }
}